// Round 4
// baseline (2065.011 us; speedup 1.0000x reference)
//
#include <hip/hip_runtime.h>

// Decoder: T=32-step attention LSTM, BATCH=LATENT=HIDDEN=1024.
// R4: dependency-repartitioned GEMMs + 32KB LDS (BK=32 dbuf) for >=3 blocks/CU.
//  per step: attn -> gemm_ctx (ctx@Wk_bot, +zh fold-in) -> lstm -> gemm_ab ([h@Wr || A2@W2])
//  z = z_lat + ctx@Wk_bot + h@Wr ; spre = s_lat + [h,c]@W2

#define T_ 32

typedef __attribute__((ext_vector_type(8))) short short8;
typedef __attribute__((ext_vector_type(4))) float f32x4;
typedef unsigned short ushort_t;

__device__ __forceinline__ unsigned short bf16u(float x) {
  unsigned int u = __float_as_uint(x);
  u += 0x7FFFu + ((u >> 16) & 1u);
  return (unsigned short)(u >> 16);
}
__device__ __forceinline__ float b2f(unsigned short u) {
  return __uint_as_float(((unsigned int)u) << 16);
}
__device__ __forceinline__ ushort4 pack4(float a, float b, float c, float d) {
  ushort4 v; v.x = bf16u(a); v.y = bf16u(b); v.z = bf16u(c); v.w = bf16u(d); return v;
}
__device__ __forceinline__ float sigmoidf_(float x) { return 1.f / (1.f + __expf(-x)); }
__device__ __forceinline__ float tanhf_(float x) { return 1.f - 2.f / (__expf(2.f * x) + 1.f); }

// ---------- transpose f32 [srcK][srcN] -> bf16 dst[n][dstStride] ----------
__global__ void k_transpose(const float* __restrict__ src, int srcN,
                            unsigned short* __restrict__ dst, int dstStride) {
  __shared__ float tile[32][33];
  int n0 = blockIdx.x * 32, k0 = blockIdx.y * 32;
  int tx = threadIdx.x, ty = threadIdx.y;
#pragma unroll
  for (int i = 0; i < 4; ++i)
    tile[ty + i * 8][tx] = src[(size_t)(k0 + ty + i * 8) * srcN + n0 + tx];
  __syncthreads();
#pragma unroll
  for (int i = 0; i < 4; ++i)
    dst[(size_t)(n0 + ty + i * 8) * dstStride + k0 + tx] = bf16u(tile[tx][ty + i * 8]);
}

// ---------- one-time init ----------
__global__ __launch_bounds__(256) void k_init(const float* __restrict__ h0,
                                              const float* __restrict__ c0,
                                              const float* __restrict__ latent,
                                              unsigned short* __restrict__ A2,
                                              unsigned short* __restrict__ latbf,
                                              float* __restrict__ c_st) {
  int r = blockIdx.x; int j = threadIdx.x * 4;
  const float4 hv = *(const float4*)&h0[(size_t)r * 1024 + j];
  const float4 cv = *(const float4*)&c0[(size_t)r * 1024 + j];
  const float4 lv = *(const float4*)&latent[(size_t)r * 1024 + j];
  *(ushort4*)&A2[(size_t)r * 2048 + j]        = pack4(hv.x, hv.y, hv.z, hv.w);
  *(ushort4*)&A2[(size_t)r * 2048 + 1024 + j] = pack4(cv.x, cv.y, cv.z, cv.w);
  *(ushort4*)&latbf[(size_t)r * 1024 + j]     = pack4(lv.x, lv.y, lv.z, lv.w);
  *(float4*)&c_st[(size_t)r * 1024 + j] = cv;
}

__global__ void k_bias(const float* __restrict__ b1, const float* __restrict__ b2,
                       float* __restrict__ bias_s) {
  int i = blockIdx.x * 256 + threadIdx.x;
  bias_s[i] = b1[i] + b2[i];
}

// ---------- GEMM core: 128x128 tile, BK=32 double-buffered (32KB LDS), T2 swizzle ----------
#define GLD(src, dst)                                                                   \
  __builtin_amdgcn_global_load_lds(                                                     \
      (const __attribute__((address_space(1))) unsigned int*)(src),                     \
      (__attribute__((address_space(3))) unsigned int*)(dst), 16, 0, 0)

__device__ __forceinline__ void gemm_core(const unsigned short* __restrict__ A, int lda,
                                          const unsigned short* __restrict__ Bt, int ldb,
                                          int row0, int col0, int kbeg, int nsteps,
                                          unsigned short* Al, unsigned short* Bl,  // [2][128*32]
                                          f32x4 acc[4][4], int w, int l) {
  const int lr = l & 15;
  const int slot = l >> 4;                         // 0..3
  const int st_row = l >> 2;                       // 0..15 within 16-row chunk
  const int st_cole = (((l & 3) ^ ((l >> 2) & 3)) << 3);  // swizzled global col (elems)
  const int wr = (w >> 1) * 64, wc = (w & 1) * 64;

  auto stage = [&](int buf, int k0) {
#pragma unroll
    for (int it = 0; it < 2; ++it) {
      int chunk = w * 2 + it;                      // wave-uniform, rows [chunk*16, +16)
      int r = chunk * 16 + st_row;
      const unsigned short* ga = A + (size_t)(row0 + r) * lda + k0 + st_cole;
      const unsigned short* gb = Bt + (size_t)(col0 + r) * ldb + k0 + st_cole;
      GLD(ga, (char*)Al + buf * 8192 + chunk * 1024);
      GLD(gb, (char*)Bl + buf * 8192 + chunk * 1024);
    }
  };

  stage(0, kbeg);
  __syncthreads();
  int cur = 0;
  for (int s = 0; s < nsteps; ++s) {
    if (s + 1 < nsteps) stage(cur ^ 1, kbeg + (s + 1) * 32);
    short8 a[4], b[4];
#pragma unroll
    for (int m = 0; m < 4; ++m) {
      int r = wr + m * 16 + lr;
      a[m] = *(const short8*)((char*)Al + cur * 8192 + r * 64 + ((slot ^ (r & 3)) << 4));
    }
#pragma unroll
    for (int n = 0; n < 4; ++n) {
      int r = wc + n * 16 + lr;
      b[n] = *(const short8*)((char*)Bl + cur * 8192 + r * 64 + ((slot ^ (r & 3)) << 4));
    }
#pragma unroll
    for (int m = 0; m < 4; ++m)
#pragma unroll
      for (int n = 0; n < 4; ++n)
        acc[m][n] = __builtin_amdgcn_mfma_f32_16x16x32_bf16(a[m], b[n], acc[m][n], 0, 0, 0);
    __syncthreads();
    cur ^= 1;
  }
}

// Generic GEMM kernel. Cf!=null: f32 out + bias[col]. Else bf16 partial out at
// Cb[z][1024][N], optionally adding b2f(addb[same idx]) (in-place fold).
__global__ __launch_bounds__(256) void k_gemm(const unsigned short* __restrict__ A, int lda,
                                              const unsigned short* __restrict__ Bt, int ldb,
                                              int Kchunk,
                                              const float* __restrict__ bias,
                                              float* __restrict__ Cf,
                                              unsigned short* __restrict__ Cb,
                                              const unsigned short* __restrict__ addb, int N) {
  __shared__ unsigned short Al[2][128 * 32];
  __shared__ unsigned short Bl[2][128 * 32];
  const int tid = threadIdx.x, w = tid >> 6, l = tid & 63;
  const int row0 = blockIdx.y * 128, col0 = blockIdx.x * 128;
  f32x4 acc[4][4] = {};
  gemm_core(A, lda, Bt, ldb, row0, col0, blockIdx.z * Kchunk, Kchunk >> 5,
            &Al[0][0], &Bl[0][0], acc, w, l);

  const int lr = l & 15, rbase = (l >> 4) * 4;
  if (Cf) {
#pragma unroll
    for (int m = 0; m < 4; ++m)
#pragma unroll
      for (int rg = 0; rg < 4; ++rg) {
        int row = row0 + (w >> 1) * 64 + m * 16 + rbase + rg;
#pragma unroll
        for (int n = 0; n < 4; ++n) {
          int col = col0 + (w & 1) * 64 + n * 16 + lr;
          Cf[(size_t)row * N + col] = acc[m][n][rg] + bias[col];
        }
      }
  } else {
    size_t zoff = (size_t)blockIdx.z * 1024 * N;
#pragma unroll
    for (int m = 0; m < 4; ++m)
#pragma unroll
      for (int rg = 0; rg < 4; ++rg) {
        int row = row0 + (w >> 1) * 64 + m * 16 + rbase + rg;
#pragma unroll
        for (int n = 0; n < 4; ++n) {
          int col = col0 + (w & 1) * 64 + n * 16 + lr;
          size_t idx = zoff + (size_t)row * N + col;
          float v = acc[m][n][rg];
          if (addb) v += b2f(addb[idx]);
          Cb[idx] = bf16u(v);
        }
      }
  }
}

// Fused [GEMM2: A2@W2t -> spre_p (8x8x4)] || [GEMM1h: h@Wrt -> zh_p (32x8x2)], 768 blocks.
__global__ __launch_bounds__(256) void k_gemm_ab(const unsigned short* __restrict__ A2,
                                                 const unsigned short* __restrict__ W2t,
                                                 const unsigned short* __restrict__ Wrt,
                                                 unsigned short* __restrict__ spre_p,
                                                 unsigned short* __restrict__ zh_p) {
  __shared__ unsigned short Al[2][128 * 32];
  __shared__ unsigned short Bl[2][128 * 32];
  const int tid = threadIdx.x, w = tid >> 6, l = tid & 63;
  int bid = blockIdx.x;
  const unsigned short *A, *Bt; unsigned short* outp;
  int lda, ldb, N, row0, col0, z;
  if (bid < 256) {          // GEMM2: [h,c]@W2t, K=2048 splitK4
    A = A2; lda = 2048; Bt = W2t; ldb = 2048; N = 1024; outp = spre_p;
    col0 = (bid & 7) * 128; row0 = ((bid >> 3) & 7) * 128; z = bid >> 6;
  } else {                  // GEMM1h: h@Wrt, K=1024 splitK2
    bid -= 256;
    A = A2; lda = 2048; Bt = Wrt; ldb = 1024; N = 4096; outp = zh_p;
    col0 = (bid & 31) * 128; row0 = ((bid >> 5) & 7) * 128; z = bid >> 8;
  }
  f32x4 acc[4][4] = {};
  gemm_core(A, lda, Bt, ldb, row0, col0, z * 512, 16, &Al[0][0], &Bl[0][0], acc, w, l);

  const int lr = l & 15, rbase = (l >> 4) * 4;
  size_t zoff = (size_t)z * 1024 * N;
#pragma unroll
  for (int m = 0; m < 4; ++m)
#pragma unroll
    for (int rg = 0; rg < 4; ++rg) {
      int row = row0 + (w >> 1) * 64 + m * 16 + rbase + rg;
#pragma unroll
      for (int n = 0; n < 4; ++n) {
        int col = col0 + (w & 1) * 64 + n * 16 + lr;
        outp[zoff + (size_t)row * N + col] = bf16u(acc[m][n][rg]);
      }
    }
}

// ---------- LSTM: z = z_lat(f32) + zsum0 + zsum1 (bf16, already ctx+h folded) ----------
__global__ __launch_bounds__(256) void k_lstm(const float* __restrict__ z_lat,
                                              const unsigned short* __restrict__ zsum,
                                              float* __restrict__ c_st,
                                              unsigned short* __restrict__ A2,
                                              const float* __restrict__ Wmu,
                                              const float* __restrict__ bmu,
                                              float* __restrict__ out, int t) {
  __shared__ float red[4];
  const size_t Z1 = (size_t)1024 * 4096;
  int r = blockIdx.x; int tid = threadIdx.x; int j = tid * 4;
  float g4[4][4];
#pragma unroll
  for (int g = 0; g < 4; ++g) {
    const float4 zl = *(const float4*)&z_lat[(size_t)r * 4096 + g * 1024 + j];
    const ushort4 p0 = *(const ushort4*)&zsum[(size_t)r * 4096 + g * 1024 + j];
    const ushort4 p1 = *(const ushort4*)&zsum[Z1 + (size_t)r * 4096 + g * 1024 + j];
    g4[g][0] = zl.x + b2f(p0.x) + b2f(p1.x);
    g4[g][1] = zl.y + b2f(p0.y) + b2f(p1.y);
    g4[g][2] = zl.z + b2f(p0.z) + b2f(p1.z);
    g4[g][3] = zl.w + b2f(p0.w) + b2f(p1.w);
  }
  const float4 cv = *(const float4*)&c_st[(size_t)r * 1024 + j];
  const float4 wm = *(const float4*)&Wmu[j];
  float cc[4] = {cv.x, cv.y, cv.z, cv.w}, wv[4] = {wm.x, wm.y, wm.z, wm.w};
  float cn[4], hn[4];
  float part = 0.f;
#pragma unroll
  for (int q = 0; q < 4; ++q) {
    float c2 = sigmoidf_(g4[1][q]) * cc[q] + sigmoidf_(g4[0][q]) * tanhf_(g4[2][q]);
    float h2 = sigmoidf_(g4[3][q]) * tanhf_(c2);
    cn[q] = c2; hn[q] = h2; part += h2 * wv[q];
  }
  *(float4*)&c_st[(size_t)r * 1024 + j] = make_float4(cn[0], cn[1], cn[2], cn[3]);
  *(ushort4*)&A2[(size_t)r * 2048 + j]        = pack4(hn[0], hn[1], hn[2], hn[3]);
  *(ushort4*)&A2[(size_t)r * 2048 + 1024 + j] = pack4(cn[0], cn[1], cn[2], cn[3]);
#pragma unroll
  for (int off = 32; off > 0; off >>= 1) part += __shfl_down(part, off, 64);
  if ((tid & 63) == 0) red[tid >> 6] = part;
  __syncthreads();
  if (tid == 0) out[(size_t)r * T_ + t] = red[0] + red[1] + red[2] + red[3] + bmu[0];
}

// ---------- attention: spre = s_lat + sum4 partials -> tanh -> softmax -> ctxb bf16 ----------
__global__ __launch_bounds__(256) void k_attn(const float* __restrict__ s_lat,
                                              const unsigned short* __restrict__ sp4,
                                              const float* __restrict__ latent,
                                              unsigned short* __restrict__ ctxb) {
  __shared__ float red[4];
  const size_t P = (size_t)1024 * 1024;
  int r = blockIdx.x; int tid = threadIdx.x; int j = tid * 4;
  const float4 sl = *(const float4*)&s_lat[(size_t)r * 1024 + j];
  float sv[4] = {sl.x, sl.y, sl.z, sl.w};
#pragma unroll
  for (int sidx = 0; sidx < 4; ++sidx) {
    const ushort4 q = *(const ushort4*)&sp4[sidx * P + (size_t)r * 1024 + j];
    sv[0] += b2f(q.x); sv[1] += b2f(q.y); sv[2] += b2f(q.z); sv[3] += b2f(q.w);
  }
  float s[4] = {tanhf_(sv[0]), tanhf_(sv[1]), tanhf_(sv[2]), tanhf_(sv[3])};
  float mx = fmaxf(fmaxf(s[0], s[1]), fmaxf(s[2], s[3]));
#pragma unroll
  for (int off = 32; off > 0; off >>= 1) mx = fmaxf(mx, __shfl_xor(mx, off, 64));
  if ((tid & 63) == 0) red[tid >> 6] = mx;
  __syncthreads();
  mx = fmaxf(fmaxf(red[0], red[1]), fmaxf(red[2], red[3]));
  __syncthreads();
  float e[4], ps = 0.f;
#pragma unroll
  for (int q = 0; q < 4; ++q) { e[q] = __expf(s[q] - mx); ps += e[q]; }
#pragma unroll
  for (int off = 32; off > 0; off >>= 1) ps += __shfl_xor(ps, off, 64);
  if ((tid & 63) == 0) red[tid >> 6] = ps;
  __syncthreads();
  float inv = 1.f / (red[0] + red[1] + red[2] + red[3]);
  const float4 lv = *(const float4*)&latent[(size_t)r * 1024 + j];
  *(ushort4*)&ctxb[(size_t)r * 1024 + j] =
      pack4(e[0] * inv * lv.x, e[1] * inv * lv.y, e[2] * inv * lv.z, e[3] * inv * lv.w);
}

extern "C" void kernel_launch(void* const* d_in, const int* in_sizes, int n_in,
                              void* d_out, int out_size, void* d_ws, size_t ws_size,
                              hipStream_t stream) {
  const float* latent = (const float*)d_in[0];
  const float* h0  = (const float*)d_in[1];
  const float* c0  = (const float*)d_in[2];
  const float* Wk  = (const float*)d_in[3];
  const float* Wr  = (const float*)d_in[4];
  const float* b   = (const float*)d_in[5];
  const float* W1  = (const float*)d_in[6];
  const float* b1  = (const float*)d_in[7];
  const float* W2  = (const float*)d_in[8];
  const float* b2  = (const float*)d_in[9];
  const float* Wmu = (const float*)d_in[10];
  const float* bmu = (const float*)d_in[11];
  float* out = (float*)d_out;

  char* p = (char*)d_ws;
  auto alloc = [&](size_t bytes) { void* r = (void*)p; p += (bytes + 255) & ~(size_t)255; return r; };
  unsigned short* Wk1_t = (unsigned short*)alloc((size_t)4096 * 1024 * 2);  // Wk top^T
  unsigned short* Wkb_t = (unsigned short*)alloc((size_t)4096 * 1024 * 2);  // Wk bottom^T
  unsigned short* Wrt   = (unsigned short*)alloc((size_t)4096 * 1024 * 2);
  unsigned short* W1t   = (unsigned short*)alloc((size_t)1024 * 1024 * 2);
  unsigned short* W2t   = (unsigned short*)alloc((size_t)1024 * 2048 * 2);
  unsigned short* latbf = (unsigned short*)alloc((size_t)1024 * 1024 * 2);
  unsigned short* A2    = (unsigned short*)alloc((size_t)1024 * 2048 * 2);  // [h | c] bf16
  unsigned short* ctxb  = (unsigned short*)alloc((size_t)1024 * 1024 * 2);
  float* z_lat  = (float*)alloc((size_t)1024 * 4096 * 4);
  float* s_lat  = (float*)alloc((size_t)1024 * 1024 * 4);
  unsigned short* zh_p   = (unsigned short*)alloc((size_t)2 * 1024 * 4096 * 2);
  unsigned short* spre_p = (unsigned short*)alloc((size_t)4 * 1024 * 1024 * 2);
  float* c_st   = (float*)alloc((size_t)1024 * 1024 * 4);
  float* bias_s = (float*)alloc((size_t)1024 * 4);

  dim3 tb(32, 8);
  k_transpose<<<dim3(128, 32), tb, 0, stream>>>(Wk, 4096, Wk1_t, 1024);
  k_transpose<<<dim3(128, 32), tb, 0, stream>>>(Wk + (size_t)1024 * 4096, 4096, Wkb_t, 1024);
  k_transpose<<<dim3(128, 32), tb, 0, stream>>>(Wr, 4096, Wrt, 1024);
  k_transpose<<<dim3(32, 64), tb, 0, stream>>>(W2, 1024, W2t, 2048);
  k_transpose<<<dim3(32, 32), tb, 0, stream>>>(W1, 1024, W1t, 1024);

  k_init<<<1024, 256, 0, stream>>>(h0, c0, latent, A2, latbf, c_st);
  k_bias<<<4, 256, 0, stream>>>(b1, b2, bias_s);

  // setup GEMMs: z_lat = latent@Wk_top + b ; s_lat = latent@W1 + (b1+b2)
  k_gemm<<<dim3(32, 8, 1), 256, 0, stream>>>(latbf, 1024, Wk1_t, 1024, 1024, b, z_lat, nullptr, nullptr, 4096);
  k_gemm<<<dim3(8, 8, 1), 256, 0, stream>>>(latbf, 1024, W1t, 1024, 1024, bias_s, s_lat, nullptr, nullptr, 1024);

  // initial spre/zh from (h0, c0)
  k_gemm_ab<<<768, 256, 0, stream>>>(A2, W2t, Wrt, spre_p, zh_p);

  for (int t = 0; t < T_; ++t) {
    k_attn<<<1024, 256, 0, stream>>>(s_lat, spre_p, latent, ctxb);
    // zsum = ctx@Wk_bot + zh (fold zh_p in-place)
    k_gemm<<<dim3(32, 8, 2), 256, 0, stream>>>(ctxb, 1024, Wkb_t, 1024, 512, nullptr, nullptr, zh_p, zh_p, 4096);
    k_lstm<<<1024, 256, 0, stream>>>(z_lat, zh_p, c_st, A2, Wmu, bmu, out, t);
    if (t < T_ - 1) k_gemm_ab<<<768, 256, 0, stream>>>(A2, W2t, Wrt, spre_p, zh_p);
  }
}